// Round 6
// baseline (187.969 us; speedup 1.0000x reference)
//
#include <hip/hip_runtime.h>
#include <cstdint>
#include <math.h>

#define HW 224
#define NPIX (HW*HW)          // 50176 = 784*64
#define BATCH 32
#define KP 64
#define PS 16
#define NCLS 1000
#define TKW 112               // 64-candidate runs per image (28 bands x 4 waves)
#define FC1_KS 16             // fc1 K-split

// ---------------------------------------------------------------------------
// Top-64 helpers: in-wave bitonic selection on packed 64-bit keys.
// key = monotone(value) << 32 | ~index  -> order == (value desc, index asc).
// ---------------------------------------------------------------------------
__device__ __forceinline__ uint64_t tk_pack(float v, int idx) {
    uint32_t u = __float_as_uint(v);
    u = (u & 0x80000000u) ? ~u : (u | 0x80000000u);
    return ((uint64_t)u << 32) | (uint32_t)(~idx);
}

__device__ __forceinline__ uint64_t tk_sort_asc(uint64_t k, int lane) {
    #pragma unroll
    for (int size = 2; size <= 64; size <<= 1) {
        #pragma unroll
        for (int stride = size >> 1; stride >= 1; stride >>= 1) {
            uint64_t o = __shfl_xor(k, stride, 64);
            bool up = ((lane & size) == 0);
            bool keepmax = (((lane & stride) != 0) == up);
            k = keepmax ? (k > o ? k : o) : (k < o ? k : o);
        }
    }
    return k;
}

__device__ __forceinline__ uint64_t tk_clean_desc(uint64_t k, int lane) {
    #pragma unroll
    for (int stride = 32; stride >= 1; stride >>= 1) {
        uint64_t o = __shfl_xor(k, stride, 64);
        bool keepmax = ((lane & stride) == 0);
        k = keepmax ? (k > o ? k : o) : (k < o ? k : o);
    }
    return k;
}

// ---------------------------------------------------------------------------
// K1: FUSED Harris + per-band top-64. One block per (8-row band, image).
// ---------------------------------------------------------------------------
__global__ __launch_bounds__(256) void k_harris_topk(const float* __restrict__ x,
                                                     uint64_t* __restrict__ cand) {
    const int r = blockIdx.x, b = blockIdx.y;
    const int tid = threadIdx.x;
    const int row0 = r * 8;
    __shared__ float G[12][228];
    __shared__ float DXs[10][228];
    __shared__ float DYs[10][228];
    __shared__ float RB[1792];
    const float* xb = x + (size_t)b * 3 * NPIX;

    // grayscale stage (stored at col+1; cols 0 and 225 are zero pads)
    for (int l = tid; l < 12 * 224; l += 256) {
        int gr = l / 224, gc = l % 224;
        int gy = row0 - 2 + gr;
        float v = 0.f;
        if (gy >= 0 && gy < HW) {
            int o = gy * HW + gc;
            v = (xb[o] + xb[NPIX + o] + xb[2 * NPIX + o]) / 3.0f;
        }
        G[gr][gc + 1] = v;
    }
    if (tid < 12) { G[tid][0] = 0.f; G[tid][225] = 0.f; }
    if (tid < 10) { DXs[tid][0] = 0.f; DXs[tid][225] = 0.f;
                    DYs[tid][0] = 0.f; DYs[tid][225] = 0.f; }
    __syncthreads();

    // Sobel dx/dy (zero outside image)
    for (int l = tid; l < 10 * 224; l += 256) {
        int dr = l / 224, dc = l % 224;
        int ay = row0 - 1 + dr;
        float dxv = 0.f, dyv = 0.f;
        if (ay >= 0 && ay < HW) {
            dxv = (G[dr][dc + 2] - G[dr][dc]) + (G[dr + 1][dc + 2] - G[dr + 1][dc]) +
                  (G[dr + 2][dc + 2] - G[dr + 2][dc]);
            dyv = (G[dr + 2][dc] + G[dr + 2][dc + 1] + G[dr + 2][dc + 2]) -
                  (G[dr][dc] + G[dr][dc + 1] + G[dr][dc + 2]);
        }
        DXs[dr][dc + 1] = dxv;
        DYs[dr][dc + 1] = dyv;
    }
    __syncthreads();

    // Harris response (masked -> exact 0)
    for (int l = tid; l < 1792; l += 256) {
        int rr = l / 224, c = l % 224;
        int gy = row0 + rr;
        float outv = 0.f;
        if (gy >= PS && gy < HW - PS && c >= PS && c < HW - PS) {
            const float gw[3][3] = {{1.f/16.f, 2.f/16.f, 1.f/16.f},
                                    {2.f/16.f, 4.f/16.f, 2.f/16.f},
                                    {1.f/16.f, 2.f/16.f, 1.f/16.f}};
            float sxx = 0.f, syy = 0.f, sxy = 0.f;
            #pragma unroll
            for (int u = 0; u < 3; u++)
                #pragma unroll
                for (int v = 0; v < 3; v++) {
                    float dv = DXs[rr + u][c + v];
                    float ev = DYs[rr + u][c + v];
                    float w = gw[u][v];
                    sxx += w * dv * dv;
                    syy += w * ev * ev;
                    sxy += w * dv * ev;
                }
            float tr = sxx + syy;
            outv = sxx * syy - sxy * sxy - 0.04f * tr * tr;
        }
        RB[l] = outv;
    }
    __syncthreads();

    // per-wave top-64 over contiguous 448-px chunk
    const int w = tid >> 6, lane = tid & 63;
    const int chunk = w * 448;
    const int gbase = row0 * 224 + chunk;
    uint64_t T = 0;
    #pragma unroll 1
    for (int it = 0; it < 7; it++) {
        float v = RB[chunk + it * 64 + lane];
        uint64_t ck = tk_pack(v, gbase + it * 64 + lane);
        uint64_t thr = __shfl(T, 63, 64);
        if (__ballot(ck > thr)) {
            uint64_t s = tk_sort_asc(ck, lane);
            uint64_t m = (T > s) ? T : s;
            T = tk_clean_desc(m, lane);
        }
    }
    cand[((size_t)b * TKW + r * 4 + w) * 64 + lane] = T;
}

// ---------------------------------------------------------------------------
// K2: merge 112 sorted runs per image.
// ---------------------------------------------------------------------------
__global__ __launch_bounds__(1024) void k_topk_merge(const uint64_t* __restrict__ cand,
                                                     int* __restrict__ kp) {
    const int img = blockIdx.x;
    const int w = threadIdx.x >> 6, lane = threadIdx.x & 63;
    const uint64_t* cb = cand + (size_t)img * TKW * 64;
    __shared__ uint64_t S[16 * 64];

    uint64_t T = cb[(w * 7) * 64 + lane];
    #pragma unroll
    for (int r = 1; r < 7; r++) {
        uint64_t C = cb[(w * 7 + r) * 64 + (63 - lane)];
        uint64_t m = (T > C) ? T : C;
        T = tk_clean_desc(m, lane);
    }
    S[w * 64 + lane] = T;
    __syncthreads();
    if (w == 0) {
        uint64_t T2 = S[lane];
        #pragma unroll
        for (int r = 1; r < 16; r++) {
            uint64_t C = S[r * 64 + (63 - lane)];
            uint64_t m = (T2 > C) ? T2 : C;
            T2 = tk_clean_desc(m, lane);
        }
        kp[img * KP + lane] = (int)(~(uint32_t)T2);
    }
}

// ---------------------------------------------------------------------------
// K3: bilinear patch extraction (faithful swapped broadcast) + conv + relu.
// Patch stored in zero-bordered LDS P[3][18][18] -> branchless 8x27 conv.
// ---------------------------------------------------------------------------
__device__ __forceinline__ float gat4(const float* img, float xf, float yf) {
    bool valid = (xf >= 0.f) && (xf < 224.f) && (yf >= 0.f) && (yf < 224.f);
    if (!valid) return 0.f;
    int xi = (int)fminf(fmaxf(xf, 0.f), 223.f);
    int yi = (int)fminf(fmaxf(yf, 0.f), 223.f);
    return img[yi * HW + xi];
}

__global__ __launch_bounds__(256) void k_patch_conv(
    const float* __restrict__ x, const int* __restrict__ kp,
    const float* __restrict__ conv_w, const float* __restrict__ conv_b,
    float* __restrict__ h) {
    const int s = blockIdx.x;   // keypoint slot
    const int b = blockIdx.y;   // image
    const int tid = threadIdx.x;

    __shared__ float P[3][18][18];   // zero border
    __shared__ float CW[216];
    __shared__ float CB[8];
    for (int l = tid; l < 216; l += 256) CW[l] = conv_w[l];
    if (tid < 8) CB[tid] = conv_b[tid];
    for (int l = tid; l < 972; l += 256) ((float*)P)[l] = 0.f;

    const int idx = kp[b * KP + s];
    const int row = idx / HW, col = idx % HW;
    float cy = ((float)row / 224.0f - 0.5f) * 2.0f;
    float cx = ((float)col / 224.0f - 0.5f) * 2.0f;
    cy = fminf(fmaxf(cy, -1.0f), 1.0f);
    cx = fminf(fmaxf(cx, -1.0f), 1.0f);
    const float y01 = (cy + 1.0f) * 0.5f;
    const float x01 = (cx + 1.0f) * 0.5f;
    const float rr = 16.0f / 224.0f;
    const float step = (2.0f * rr) / 15.0f;
    const float* xb = x + (size_t)b * 3 * NPIX;
    __syncthreads();

    for (int e = tid; e < 768; e += 256) {
        int c = e >> 8, rem = e & 255, i = rem >> 4, j = rem & 15;
        float pj = (j == 15) ? rr : (-rr + (float)j * step);
        float pi = (i == 15) ? rr : (-rr + (float)i * step);
        // faithful bug: x-coordinate uses y01 (row), y-coordinate uses x01 (col)
        float gxn = (pj + y01) * 2.0f - 1.0f;
        float gyn = (pi + x01) * 2.0f - 1.0f;
        float gx = (gxn + 1.0f) * 0.5f * 223.0f;
        float gy = (gyn + 1.0f) * 0.5f * 223.0f;
        float x0 = floorf(gx), y0 = floorf(gy);
        float x1 = x0 + 1.0f, y1 = y0 + 1.0f;
        float wx1 = gx - x0, wy1 = gy - y0;
        float wx0 = 1.0f - wx1, wy0 = 1.0f - wy1;
        const float* img = xb + (size_t)c * NPIX;
        float acc = gat4(img, x0, y0) * (wx0 * wy0)
                  + gat4(img, x1, y0) * (wx1 * wy0)
                  + gat4(img, x0, y1) * (wx0 * wy1)
                  + gat4(img, x1, y1) * (wx1 * wy1);
        P[c][i + 1][j + 1] = acc;
    }
    __syncthreads();

    const int i = tid >> 4, j = tid & 15;
    const size_t mbase = ((size_t)(b * KP + s)) * 2048;
    #pragma unroll
    for (int co = 0; co < 8; co++) {
        float acc = CB[co];
        #pragma unroll
        for (int ci = 0; ci < 3; ci++)
            #pragma unroll
            for (int di = 0; di < 3; di++)
                #pragma unroll
                for (int dj = 0; dj < 3; dj++)
                    acc += P[ci][i + di][j + dj] * CW[co * 27 + ci * 9 + di * 3 + dj];
        h[mbase + co * 256 + tid] = fmaxf(acc, 0.0f);
    }
}

// ---------------------------------------------------------------------------
// K4: fc1 partial GEMM. grid (32 m-tiles, 16 k-slices) x 256.
// ---------------------------------------------------------------------------
__global__ __launch_bounds__(256) void k_fc1(
    const float* __restrict__ h, const float* __restrict__ fc1_w,
    float* __restrict__ partial) {
    const int mt = blockIdx.x;          // 0..31
    const int ks = blockIdx.y;          // 0..15
    const int tid = threadIdx.x;
    const int M0 = mt * 64;
    const int og = tid >> 4, mg = tid & 15;
    __shared__ float A[64 * 68];        // [k][m]
    __shared__ float W[64 * 68];        // [k][o]
    float acc[4][4];
    #pragma unroll
    for (int i = 0; i < 4; i++)
        #pragma unroll
        for (int j = 0; j < 4; j++) acc[i][j] = 0.f;

    #pragma unroll 1
    for (int ch = 0; ch < 2; ch++) {
        const int k0 = ks * 128 + ch * 64;
        __syncthreads();
        #pragma unroll
        for (int p = 0; p < 4; p++) {
            int row = p * 16 + (tid >> 4);      // 0..63
            int c0 = (tid & 15) * 4;            // k offset 0..60
            float4 av = *(const float4*)&h[(size_t)(M0 + row) * 2048 + k0 + c0];
            A[(c0 + 0) * 68 + row] = av.x;
            A[(c0 + 1) * 68 + row] = av.y;
            A[(c0 + 2) * 68 + row] = av.z;
            A[(c0 + 3) * 68 + row] = av.w;
            float4 wv = *(const float4*)&fc1_w[(size_t)row * 2048 + k0 + c0];
            W[(c0 + 0) * 68 + row] = wv.x;
            W[(c0 + 1) * 68 + row] = wv.y;
            W[(c0 + 2) * 68 + row] = wv.z;
            W[(c0 + 3) * 68 + row] = wv.w;
        }
        __syncthreads();
        #pragma unroll 4
        for (int k = 0; k < 64; k++) {
            float4 a = *(float4*)&A[k * 68 + mg * 4];
            float4 w = *(float4*)&W[k * 68 + og * 4];
            acc[0][0] += a.x * w.x; acc[0][1] += a.x * w.y;
            acc[0][2] += a.x * w.z; acc[0][3] += a.x * w.w;
            acc[1][0] += a.y * w.x; acc[1][1] += a.y * w.y;
            acc[1][2] += a.y * w.z; acc[1][3] += a.y * w.w;
            acc[2][0] += a.z * w.x; acc[2][1] += a.z * w.y;
            acc[2][2] += a.z * w.z; acc[2][3] += a.z * w.w;
            acc[3][0] += a.w * w.x; acc[3][1] += a.w * w.y;
            acc[3][2] += a.w * w.z; acc[3][3] += a.w * w.w;
        }
    }
    float* pb = partial + ((size_t)ks * 2048 + M0) * 64;
    #pragma unroll
    for (int mi = 0; mi < 4; mi++) {
        float4 v = make_float4(acc[mi][0], acc[mi][1], acc[mi][2], acc[mi][3]);
        *(float4*)&pb[(mg * 4 + mi) * 64 + og * 4] = v;
    }
}

// Sum 16 partials + bias + relu -> featT; also seed out[b][c] = fc2_b[c].
__global__ __launch_bounds__(256) void k_fc1_post(
    const float* __restrict__ partial, const float* __restrict__ fc1_b,
    const float* __restrict__ fc2_b, float* __restrict__ featT,
    float* __restrict__ out) {
    const int id = blockIdx.x * 256 + threadIdx.x;   // 0..131071
    const int o = id & 63, m = id >> 6;
    float s = 0.f;
    #pragma unroll
    for (int ks = 0; ks < FC1_KS; ks++) s += partial[(size_t)ks * 131072 + id];
    s = fmaxf(s + fc1_b[o], 0.f);
    featT[(size_t)((m & 63) * 64 + o) * 32 + (m >> 6)] = s;
    if (id < BATCH * NCLS) out[id] = fc2_b[id % NCLS];
}

// ---------------------------------------------------------------------------
// K5: fc2 out[b][c] += sum_k featT[k][b]*fc2_w[c][k], K split 32 ways.
// grid (125, 32): 8 classes x single K-chunk of 128. No serial chunk loop.
// ---------------------------------------------------------------------------
__global__ __launch_bounds__(256) void k_fc2(
    const float* __restrict__ featT, const float* __restrict__ fc2_w,
    float* __restrict__ out) {
    const int c0 = blockIdx.x * 8;
    const int k0 = blockIdx.y * 128;
    const int tid = threadIdx.x;
    const int b = tid & 31, kg = tid >> 5;
    __shared__ float F[128 * 36];
    __shared__ float Wc[8 * 128];
    __shared__ float Red[8 * 8 * 32];

    #pragma unroll
    for (int r = 0; r < 4; r++) {
        int l = tid + r * 256;
        int f = l >> 3, b4 = (l & 7) << 2;
        *(float4*)&F[f * 36 + b4] =
            *(const float4*)&featT[(size_t)(k0 + f) * 32 + b4];
    }
    {
        int cl = tid >> 5, koff = (tid & 31) << 2;
        *(float4*)&Wc[cl * 128 + koff] =
            *(const float4*)&fc2_w[(size_t)(c0 + cl) * 4096 + k0 + koff];
    }
    __syncthreads();

    float acc[8];
    #pragma unroll
    for (int cl = 0; cl < 8; cl++) acc[cl] = 0.f;
    #pragma unroll
    for (int cl = 0; cl < 8; cl++) {
        #pragma unroll
        for (int i = 0; i < 16; i += 4) {
            float4 wv = *(float4*)&Wc[cl * 128 + kg * 16 + i];
            int f = kg * 16 + i;
            acc[cl] += wv.x * F[f * 36 + b] + wv.y * F[(f + 1) * 36 + b] +
                       wv.z * F[(f + 2) * 36 + b] + wv.w * F[(f + 3) * 36 + b];
        }
    }
    __syncthreads();
    #pragma unroll
    for (int cl = 0; cl < 8; cl++) Red[(kg * 8 + cl) * 32 + b] = acc[cl];
    __syncthreads();
    const int cl2 = tid >> 5, b2 = tid & 31;
    float s = 0.f;
    #pragma unroll
    for (int g = 0; g < 8; g++) s += Red[(g * 8 + cl2) * 32 + b2];
    atomicAdd(&out[b2 * NCLS + c0 + cl2], s);
}

// ---------------------------------------------------------------------------
extern "C" void kernel_launch(void* const* d_in, const int* in_sizes, int n_in,
                              void* d_out, int out_size, void* d_ws, size_t ws_size,
                              hipStream_t stream) {
    const float* x      = (const float*)d_in[0];
    const float* conv_w = (const float*)d_in[1];
    const float* conv_b = (const float*)d_in[2];
    const float* fc1_w  = (const float*)d_in[3];
    const float* fc1_b  = (const float*)d_in[4];
    const float* fc2_w  = (const float*)d_in[5];
    const float* fc2_b  = (const float*)d_in[6];
    float* out = (float*)d_out;

    // ws layout. Region0 (8.39 MB): cand (1.84 MB) early, then reused as
    // fc1 partial[16][2048][64] — cand is dead before k_fc1 (stream-ordered).
    char* base = (char*)d_ws;
    const size_t region0 = (size_t)FC1_KS * 2048 * 64 * 4;       // 8.39 MB
    uint64_t* cand    = (uint64_t*)base;                         // 1.84 MB
    float*    partial = (float*)base;                            // alias
    float*    h       = (float*)(base + region0);                // 16.78 MB
    float*    featT   = h + (size_t)2048 * 2048;                 // 0.52 MB
    int*      kp      = (int*)(featT + (size_t)4096 * 32);       // 8 KB

    k_harris_topk<<<dim3(28, 32), 256, 0, stream>>>(x, cand);
    k_topk_merge<<<32, 1024, 0, stream>>>(cand, kp);
    k_patch_conv<<<dim3(KP, BATCH), 256, 0, stream>>>(x, kp, conv_w, conv_b, h);
    k_fc1<<<dim3(32, FC1_KS), 256, 0, stream>>>(h, fc1_w, partial);
    k_fc1_post<<<512, 256, 0, stream>>>(partial, fc1_b, fc2_b, featT, out);
    k_fc2<<<dim3(125, 32), 256, 0, stream>>>(featT, fc2_w, out);
}